// Round 3
// baseline (630.802 us; speedup 1.0000x reference)
//
#include <hip/hip_runtime.h>

#define B_ 64
#define T_ 1024
#define V_ 512
#define L_ 128
#define LOG2E_ 1.4426950408889634f
#define LN2_   0.6931471805599453f

typedef float f4_t __attribute__((ext_vector_type(4)));
typedef float f2_t __attribute__((ext_vector_type(2)));

__device__ __forceinline__ float exp2_fast(float x) { return __builtin_amdgcn_exp2f(x); }
__device__ __forceinline__ float log2_fast(float x) { return __builtin_amdgcn_logf(x); }
__device__ __forceinline__ float ldx(float v, int e) { return __builtin_amdgcn_ldexpf(v, e); }

// wave shift-up-by-1 (lane i <- lane i-1, lane0 -> 0): DPP wave_shr:1
__device__ __forceinline__ float dpp_shr1_f(float x) {
    return __int_as_float(__builtin_amdgcn_update_dpp(0, __float_as_int(x), 0x138, 0xf, 0xf, true));
}
__device__ __forceinline__ int dpp_shr1_i(int x) {
    return __builtin_amdgcn_update_dpp(0, x, 0x138, 0xf, 0xf, true);
}
__device__ __forceinline__ float ag_loadf(const float* p) {
    return __hip_atomic_load((float*)p, __ATOMIC_RELAXED, __HIP_MEMORY_SCOPE_AGENT);
}
__device__ __forceinline__ void ag_storef(float* p, float v) {
    __hip_atomic_store(p, v, __ATOMIC_RELAXED, __HIP_MEMORY_SCOPE_AGENT);
}

// =================== multi-block chained pipeline ===================
// R2 post-mortem: 209 cyc/row == one CU's L1-miss machinery ingesting the
// whole 2MB [T,V] slice for its batch item; 192/256 CUs idle. Split each b
// across JB_=4 chained blocks (grid=256, 1 block/CU via 133KB LDS): staging
// becomes a concurrent whole-GPU phase (~HBM-bound), the serial recursion
// hops blocks via exact (f32,int) per-lane state handoff through AGENT-scope
// atomics. Dependencies point to strictly lower blockIdx (j-major grid) =>
// in-order placement can never deadlock.
#define JB_   4            // blocks per batch item
#define RPB_  256          // rows (timesteps) per block
#define PPB_  128          // row-pairs per block
#define PRW_  260          // words per pair: [eb0,eb1][e1 f2 x64][e3 f2 x64][pad2]
#define WS_FLAG_I_ 256     // int index of handoff flags in ws
#define WS_HOFF_F_ 1024    // float index of handoff data in ws
#define WS_NEED_   (4096 + (size_t)B_*JB_*384*4)

__global__ __launch_bounds__(512, 1) void ctc_alpha_mb(
    const float* __restrict__ outputs, const int* __restrict__ labels,
    const int* __restrict__ out_lens, const int* __restrict__ lab_lens,
    float* __restrict__ ws, float* __restrict__ out)
{
    const int j    = blockIdx.x >> 6;      // 0..3 (j-major: all j=0 blocks first)
    const int b    = blockIdx.x & 63;
    const int tid  = threadIdx.x;
    const int wid  = tid >> 6;
    const int lane = tid & 63;

    int*   cnt    = (int*)ws;
    float* losses = ws + 16;

    __shared__ float pairbuf[PPB_ * PRW_];   // 133,120 B -> 1 block/CU
    __shared__ int   prog[8];                // rows staged (absolute end) per wave
    __shared__ float save2[2];
    __shared__ int   saveE[2];

    const int olen  = out_lens[b];
    const int ll    = lab_lens[b];
    const int s0q   = 2 * ll - 1;
    const int s1q   = 2 * ll;
    const int tlast = olen - 1;
    const int l0  = s0q >> 2, j0 = s0q & 3;
    const int l1e = (s1q == 256) ? 63 : (s1q >> 2);
    const int j1  = s1q & 3;
    const float* base = outputs + (size_t)b * T_ * V_;
    const int*   lab  = labels + b * L_;

    const int cA = lab[2 * lane];          // col for state 4l+1
    const int cB = lab[2 * lane + 1];      // col for state 4l+3

    if (tid < 8) prog[tid] = 0;
    __syncthreads();

    if (wid > 0) {
        // ---------------- producers: stage this block's 256 rows ----------------
        __builtin_amdgcn_s_setprio(0);
        const int w    = wid;                       // 1..7
        const int segS = (w - 1) * 38;              // even
        const int segE = (w < 7) ? segS + 38 : RPB_;
        for (int g = segS; g < segE; g += 8) {
            const int n = (segE - g >= 8) ? 8 : (segE - g);   // 8, 6, or 4 (even)
            float gb[8], g1[8], g3[8];
            #pragma unroll
            for (int m = 0; m < 8; ++m) {
                int rr = (m < n) ? (g + m) : g;
                const float* rp = base + (size_t)(RPB_ * j + rr) * V_;
                gb[m] = rp[0];       // blank col: uniform -> broadcast txn
                g1[m] = rp[cA];
                g3[m] = rp[cB];
            }
            #pragma unroll
            for (int m = 0; m < 8; m += 2) {
                if (m < n) {
                    int pr = (g + m) >> 1;
                    f2_t* d2 = (f2_t*)&pairbuf[pr * PRW_];
                    f2_t e1p, e3p;
                    e1p.x = exp2_fast(g1[m] * LOG2E_);   e1p.y = exp2_fast(g1[m+1] * LOG2E_);
                    e3p.x = exp2_fast(g3[m] * LOG2E_);   e3p.y = exp2_fast(g3[m+1] * LOG2E_);
                    d2[1 + lane]  = e1p;   // contiguous f2/lane: conflict-free
                    d2[65 + lane] = e3p;
                    if (lane == 0) {
                        f2_t ebp;
                        ebp.x = exp2_fast(gb[m] * LOG2E_); ebp.y = exp2_fast(gb[m+1] * LOG2E_);
                        d2[0] = ebp;
                    }
                }
            }
            if (lane == 0)   // release orders the wave's ds_writes before prog
                __hip_atomic_store(&prog[w], g + n, __ATOMIC_RELEASE, __HIP_MEMORY_SCOPE_WORKGROUP);
        }
        return;   // producers done; no trailing barrier
    }

    // ---------------- consumer: wave 0 ----------------
    __builtin_amdgcn_s_setprio(3);

    float sk1 = 0.f, sk3 = 0.f;
    sk3 = (cB != cA) ? 1.f : 0.f;
    if (lane >= 1) sk1 = (cA != lab[2 * lane - 1]) ? 1.f : 0.f;

    float v0 = 0.f, v1 = 0.f, v2 = 0.f, v3 = 0.f, vx = 0.f;
    int   E = 0;
    const bool isl0 = (lane == 0);

    const int  lim      = tlast - RPB_ * j;         // last local row to step
    const bool hasHere  = (lim >= 0) && (lim < RPB_);
    const bool doPublish= (lim >= RPB_);            // chain continues past us
    if (lim < 0) return;                            // tlast before our range: idle

    int avail = 0;
    auto ensureAvail = [&](int need) {              // need = highest row required
        if (need < avail) return;
        int w = need / 38 + 1; if (w > 7) w = 7;
        int p = __hip_atomic_load(&prog[w], __ATOMIC_ACQUIRE, __HIP_MEMORY_SCOPE_WORKGROUP);
        while (p <= need) {
            __builtin_amdgcn_s_sleep(2);
            p = __hip_atomic_load(&prog[w], __ATOMIC_ACQUIRE, __HIP_MEMORY_SCOPE_WORKGROUP);
        }
        avail = p;
    };

    auto step = [&](float eb, float e1, float e3) {
        float up1 = dpp_shr1_f(v3);
        int   upE = dpp_shr1_i(E);
        upE = isl0 ? E : upE;
        int d    = upE - E;
        int mpos = (d > 0) ? d : 0;
        int sin  = (d < 0) ? d : 0;
        int sown = -mpos;
        E += mpos;
        v0 = ldx(v0, sown); v1 = ldx(v1, sown); v2 = ldx(v2, sown);
        v3 = ldx(v3, sown); vx = ldx(vx, sown);
        up1 = ldx(up1, sin);
        float n0 = (v0 + up1) * eb;
        float n1 = fmaf(sk1, up1, v1 + v0) * e1;
        float n2 = (v2 + v1) * eb;
        float n3 = fmaf(sk3, v1, v3 + v2) * e3;
        vx = (vx + v3) * eb;
        v0 = n0; v1 = n1; v2 = n2; v3 = n3;
    };
    auto renorm = [&]() {
        float mx = fmaxf(fmaxf(v0, v1), fmaxf(v2, v3));
        mx = fmaxf(mx, vx);
        int ex = (__float_as_int(mx) >> 23) - 126;
        v0 = ldx(v0, -ex); v1 = ldx(v1, -ex); v2 = ldx(v2, -ex); v3 = ldx(v3, -ex);
        vx = ldx(vx, -ex);
        E += ex;
    };
    auto saveState = [&]() {
        float w0 = (j0==0)?v0:(j0==1)?v1:(j0==2)?v2:v3;
        float w1 = (s1q==256) ? vx : ((j1==0)?v0:(j1==1)?v1:(j1==2)?v2:v3);
        if (lane == l0)  { save2[0] = w0; saveE[0] = E; }
        if (lane == l1e) { save2[1] = w1; saveE[1] = E; }
    };
    auto doRowDirect = [&](int r) {
        ensureAvail(r);
        const float* d = &pairbuf[(r >> 1) * PRW_];
        float eb = d[r & 1];
        float e1 = d[2   + 2*lane + (r & 1)];
        float e3 = d[130 + 2*lane + (r & 1)];
        step(eb, e1, e3);
        if ((r & 3) == 3) renorm();
        if (r == lim) saveState();
    };

    int loopStart;
    if (j == 0) {
        // init alpha at t=0
        v0 = exp2_fast(base[0]      * LOG2E_);
        v1 = exp2_fast(base[lab[0]] * LOG2E_);
        v0 = isl0 ? v0 : 0.f;
        v1 = isl0 ? v1 : 0.f;
        if (tlast == 0) saveState();
        // prologue rows 1..3 (keeps fast-loop start parity even)
        if (lim >= 1) doRowDirect(1);
        if (lim >= 2) doRowDirect(2);
        if (lim >= 3) doRowDirect(3);
        loopStart = 2;
    } else {
        // wait for upstream block's handoff (device-scope, L1-bypassing)
        int* flag = (int*)ws + WS_FLAG_I_ + b * JB_ + (j - 1);
        if (lane == 0) {
            while (__hip_atomic_load(flag, __ATOMIC_ACQUIRE, __HIP_MEMORY_SCOPE_AGENT) == 0)
                __builtin_amdgcn_s_sleep(4);
        }
        const float* h = ws + WS_HOFF_F_ + (size_t)(b * JB_ + (j - 1)) * 384 + lane * 6;
        v0 = ag_loadf(h + 0); v1 = ag_loadf(h + 1); v2 = ag_loadf(h + 2);
        v3 = ag_loadf(h + 3); vx = ag_loadf(h + 4);
        E  = __float_as_int(ag_loadf(h + 5));
        loopStart = 0;
    }

    const int fp = doPublish ? PPB_ : (lim >> 1);   // pairs strictly below the save row
    const f2_t* pb2 = (const f2_t*)&pairbuf[0];

    if (fp > loopStart) {
        // 2-slot ring with NAMED registers (static indexing; rule-#20-safe)
        f2_t rEB0, rE10, rE30, rEB1, rE11, rE31;
        ensureAvail(2 * loopStart + 3);
        rEB0 = pb2[loopStart*130];       rE10 = pb2[loopStart*130 + 1 + lane];       rE30 = pb2[loopStart*130 + 65 + lane];
        rEB1 = pb2[(loopStart+1)*130];   rE11 = pb2[(loopStart+1)*130 + 1 + lane];   rE31 = pb2[(loopStart+1)*130 + 65 + lane];

        int pp = loopStart;
        #pragma unroll 2
        for (; pp + 1 < fp; pp += 2) {
            // even pair (slot 0)
            {
                f2_t eb = rEB0, e1 = rE10, e3 = rE30;
                int pn = pp + 2;
                if (pn < PPB_) {
                    ensureAvail(2 * pn + 1);
                    rEB0 = pb2[pn*130]; rE10 = pb2[pn*130 + 1 + lane]; rE30 = pb2[pn*130 + 65 + lane];
                }
                step(eb.x, e1.x, e3.x);
                step(eb.y, e1.y, e3.y);
            }
            // odd pair (slot 1) + renorm (rows ...r==3 mod 4)
            {
                f2_t eb = rEB1, e1 = rE11, e3 = rE31;
                int pn = pp + 3;
                if (pn < PPB_) {
                    ensureAvail(2 * pn + 1);
                    rEB1 = pb2[pn*130]; rE11 = pb2[pn*130 + 1 + lane]; rE31 = pb2[pn*130 + 65 + lane];
                }
                step(eb.x, e1.x, e3.x);
                step(eb.y, e1.y, e3.y);
                renorm();
            }
        }
        if (pp < fp) {   // leftover even pair (fp odd), no renorm
            f2_t eb = rEB0, e1 = rE10, e3 = rE30;
            step(eb.x, e1.x, e3.x);
            step(eb.y, e1.y, e3.y);
        }
    }

    if (hasHere) {
        // careful tail rows [2*fp .. lim] with save at lim
        int rs = 2 * fp;
        if (j == 0 && rs < 4) rs = 4;   // rows 1..3 done in prologue
        for (int r = rs; r <= lim; ++r) doRowDirect(r);

        // -------- fused finish: per-batch loss + last-block mean (wave0 only) ----
        int am = 0;
        if (lane == 0) {
            float lx = log2_fast(save2[0]) + (float)saveE[0];
            float ly = log2_fast(save2[1]) + (float)saveE[1];
            float m  = fmaxf(lx, ly);
            float lik2 = m + log2_fast(exp2_fast(lx - m) + exp2_fast(ly - m));
            float loss = -(lik2 * LN2_) / (float)ll;
            ag_storef(&losses[b], loss);
            int old = __hip_atomic_fetch_add(cnt, 1, __ATOMIC_ACQ_REL, __HIP_MEMORY_SCOPE_AGENT);
            am = (old == B_ - 1);
        }
        am = __shfl(am, 0);
        if (am) {
            float v = ag_loadf(&losses[lane]);
            #pragma unroll
            for (int o = 32; o > 0; o >>= 1) v += __shfl_down(v, o);
            if (lane == 0) out[0] = v * (1.0f / B_);
        }
    } else if (doPublish) {
        // hand exact per-lane state to block j+1
        float* h = ws + WS_HOFF_F_ + (size_t)(b * JB_ + j) * 384 + lane * 6;
        ag_storef(h + 0, v0); ag_storef(h + 1, v1); ag_storef(h + 2, v2);
        ag_storef(h + 3, v3); ag_storef(h + 4, vx);
        ag_storef(h + 5, __int_as_float(E));
        if (lane == 0)   // release waits wave-wide vmcnt -> all lanes' stores visible
            __hip_atomic_store((int*)ws + WS_FLAG_I_ + b * JB_ + j, 1,
                               __ATOMIC_RELEASE, __HIP_MEMORY_SCOPE_AGENT);
    }
}

// =================== fallback: R2 single-block kernel (ws too small) ===================
#define C_ 56
#define RW4_ 65
#define NC_ ((T_ - 1 + C_ - 1) / C_)

__global__ __launch_bounds__(512, 1) void ctc_alpha_fb(
    const float* __restrict__ outputs, const int* __restrict__ labels,
    const int* __restrict__ out_lens, const int* __restrict__ lab_lens,
    float* __restrict__ ws, float* __restrict__ out)
{
    const int b    = blockIdx.x;
    const int tid  = threadIdx.x;
    const int wid  = tid >> 6;
    const int lane = tid & 63;

    int* cnt = (int*)ws;
    float* losses = ws + 16;

    __shared__ f4_t  ring4[2][C_ * RW4_];
    __shared__ float save2[2];
    __shared__ int   saveE[2];
    __shared__ int   amLast;

    const int olen  = out_lens[b];
    const int ll    = lab_lens[b];
    const int s0q   = 2 * ll - 1;
    const int s1q   = 2 * ll;
    const int tlast = olen - 1;
    const int l0  = s0q >> 2, j0 = s0q & 3;
    const int l1e = (s1q == 256) ? 63 : (s1q >> 2);
    const int j1  = s1q & 3;
    const float* base = outputs + (size_t)b * T_ * V_;
    const int*   lab  = labels + b * L_;

    const int cA = lab[2 * lane];
    const int cB = lab[2 * lane + 1];

    float sk1 = 0.f, sk3 = 0.f;
    float v0 = 0.f, v1 = 0.f, v2 = 0.f, v3 = 0.f, vx = 0.f;
    int   E = 0;
    const bool isl0 = (lane == 0);
    if (wid == 0) {
        __builtin_amdgcn_s_setprio(3);
        sk3 = (cB != cA) ? 1.f : 0.f;
        if (lane >= 1) sk1 = (cA != lab[2 * lane - 1]) ? 1.f : 0.f;
        if (isl0) {
            v0 = exp2_fast(base[0]      * LOG2E_);
            v1 = exp2_fast(base[lab[0]] * LOG2E_);
        }
        if (tlast == 0) {
            float w0 = (j0==0)?v0:(j0==1)?v1:(j0==2)?v2:v3;
            float w1 = (s1q==256) ? vx : ((j1==0)?v0:(j1==1)?v1:(j1==2)?v2:v3);
            if (lane == l0)  { save2[0] = w0; saveE[0] = E; }
            if (lane == l1e) { save2[1] = w1; saveE[1] = E; }
        }
    } else {
        __builtin_amdgcn_s_setprio(0);
    }

    auto produce = [&](int bb, int t0) {
        float gb[8], g1[8], g3[8];
        #pragma unroll
        for (int m = 0; m < 8; ++m) {
            int t = t0 + (wid - 1) + 7 * m;
            const float* rp = (t < T_) ? (base + (size_t)t * V_) : base;
            gb[m] = rp[0]; g1[m] = rp[cA]; g3[m] = rp[cB];
        }
        #pragma unroll
        for (int m = 0; m < 8; ++m) {
            int r = (wid - 1) + 7 * m;
            int t = t0 + r;
            if (t < T_) {
                f4_t e;
                e.x = exp2_fast(gb[m] * LOG2E_);
                e.y = exp2_fast(g1[m] * LOG2E_);
                e.z = exp2_fast(g3[m] * LOG2E_);
                e.w = 0.f;
                ring4[bb][r * RW4_ + lane] = e;
            }
        }
    };

    auto step = [&](f4_t e) {
        float up1 = dpp_shr1_f(v3);
        int   upE = dpp_shr1_i(E);
        upE = isl0 ? E : upE;
        int d    = upE - E;
        int mpos = (d > 0) ? d : 0;
        int sin  = (d < 0) ? d : 0;
        int sown = -mpos;
        E += mpos;
        v0 = ldx(v0, sown); v1 = ldx(v1, sown); v2 = ldx(v2, sown);
        v3 = ldx(v3, sown); vx = ldx(vx, sown);
        up1 = ldx(up1, sin);
        float n0 = (v0 + up1) * e.x;
        float n1 = fmaf(sk1, up1, v1 + v0) * e.y;
        float n2 = (v2 + v1) * e.x;
        float n3 = fmaf(sk3, v1, v3 + v2) * e.z;
        vx = (vx + v3) * e.x;
        v0 = n0; v1 = n1; v2 = n2; v3 = n3;
    };

    auto renorm = [&]() {
        float mx = fmaxf(fmaxf(v0, v1), fmaxf(v2, v3));
        mx = fmaxf(mx, vx);
        int ex = (__float_as_int(mx) >> 23) - 126;
        v0 = ldx(v0, -ex); v1 = ldx(v1, -ex); v2 = ldx(v2, -ex); v3 = ldx(v3, -ex);
        vx = ldx(vx, -ex);
        E += ex;
    };

    auto consume = [&](int bb, int t0) {
        const f4_t* rp4 = &ring4[bb][lane];
        f4_t eb2[2];
        eb2[0] = rp4[0];
        eb2[1] = rp4[RW4_];
        bool chk = (t0 + C_ > T_) || ((unsigned)(tlast - t0) < (unsigned)C_);
        if (!chk) {
            #pragma unroll 8
            for (int r = 0; r < C_; ++r) {
                f4_t e = eb2[r & 1];
                if (r + 2 < C_) eb2[r & 1] = rp4[(r + 2) * RW4_];
                step(e);
                if ((r & 3) == 3) renorm();
            }
        } else {
            #pragma unroll 4
            for (int r = 0; r < C_; ++r) {
                int t = t0 + r;
                if (t >= T_) break;
                f4_t e = eb2[r & 1];
                if (r + 2 < C_) eb2[r & 1] = rp4[(r + 2) * RW4_];
                step(e);
                if ((r & 3) == 3) renorm();
                if (t == tlast) {
                    float w0 = (j0==0)?v0:(j0==1)?v1:(j0==2)?v2:v3;
                    float w1 = (s1q==256) ? vx : ((j1==0)?v0:(j1==1)?v1:(j1==2)?v2:v3);
                    if (lane == l0)  { save2[0] = w0; saveE[0] = E; }
                    if (lane == l1e) { save2[1] = w1; saveE[1] = E; }
                }
            }
        }
    };

    if (wid > 0) produce(0, 1);
    __syncthreads();
    for (int c = 0; c < NC_; ++c) {
        if (wid > 0) {
            if (c + 1 < NC_) produce((c + 1) & 1, 1 + (c + 1) * C_);
        } else {
            consume(c & 1, 1 + c * C_);
        }
        __syncthreads();
    }

    if (tid == 0) {
        float lx = log2_fast(save2[0]) + (float)saveE[0];
        float ly = log2_fast(save2[1]) + (float)saveE[1];
        float m  = fmaxf(lx, ly);
        float lik2 = m + log2_fast(exp2_fast(lx - m) + exp2_fast(ly - m));
        float loss = -(lik2 * LN2_) / (float)ll;
        __hip_atomic_store(&losses[b], loss, __ATOMIC_RELAXED, __HIP_MEMORY_SCOPE_AGENT);
        int old = __hip_atomic_fetch_add(cnt, 1, __ATOMIC_ACQ_REL, __HIP_MEMORY_SCOPE_AGENT);
        amLast = (old == B_ - 1);
    }
    __syncthreads();
    if (amLast && wid == 0) {
        float v = __hip_atomic_load(&losses[lane], __ATOMIC_RELAXED, __HIP_MEMORY_SCOPE_AGENT);
        #pragma unroll
        for (int o = 32; o > 0; o >>= 1) v += __shfl_down(v, o);
        if (lane == 0) out[0] = v * (1.0f / B_);
    }
}

extern "C" void kernel_launch(void* const* d_in, const int* in_sizes, int n_in,
                              void* d_out, int out_size, void* d_ws, size_t ws_size,
                              hipStream_t stream) {
    const float* outputs  = (const float*)d_in[0];
    const int*   labels   = (const int*)d_in[1];
    const int*   out_lens = (const int*)d_in[2];
    const int*   lab_lens = (const int*)d_in[3];

    if (ws_size >= WS_NEED_) {
        (void)hipMemsetAsync(d_ws, 0, 2048, stream);   // cnt + losses + handoff flags
        ctc_alpha_mb<<<B_ * JB_, 512, 0, stream>>>(outputs, labels, out_lens, lab_lens,
                                                   (float*)d_ws, (float*)d_out);
    } else {
        (void)hipMemsetAsync(d_ws, 0, 64, stream);
        ctc_alpha_fb<<<B_, 512, 0, stream>>>(outputs, labels, out_lens, lab_lens,
                                             (float*)d_ws, (float*)d_out);
    }
}

// Round 4
// 224.640 us; speedup vs baseline: 2.8081x; 2.8081x over previous
//
#include <hip/hip_runtime.h>

#define B_ 64
#define T_ 1024
#define V_ 512
#define L_ 128
#define LOG2E_ 1.4426950408889634f
#define LN2_   0.6931471805599453f
#define C_ 56           // timestep rows per chunk (7 producer waves x 8 rows)
#define RW4_ 65         // ring row stride in f4 (260 floats, 1040 B) - R2-proven
#define NC_ ((T_ - 1 + C_ - 1) / C_)   // 19 chunks cover t = 1..1023

typedef float f4_t __attribute__((ext_vector_type(4)));

__device__ __forceinline__ float exp2_fast(float x) { return __builtin_amdgcn_exp2f(x); }
__device__ __forceinline__ float log2_fast(float x) { return __builtin_amdgcn_logf(x); }
__device__ __forceinline__ float ldx(float v, int e) { return __builtin_amdgcn_ldexpf(v, e); }

// wave shift-up-by-1 (lane i <- lane i-1, lane0 -> 0): DPP wave_shr:1
__device__ __forceinline__ float dpp_shr1_f(float x) {
    return __int_as_float(__builtin_amdgcn_update_dpp(0, __float_as_int(x), 0x138, 0xf, 0xf, true));
}
__device__ __forceinline__ int dpp_shr1_i(int x) {
    return __builtin_amdgcn_update_dpp(0, x, 0x138, 0xf, 0xf, true);
}

// One block (8 waves) per batch item. (R3's cross-block chain reverted: warm
// replays showed ~100us/hop flag-propagation latency across XCD L2s.)
//  wave 0   : scaled LINEAR-domain alpha recursion - byte-identical to the
//             proven 92us R2 consumer (1 conflict-free ds_read_b128/step,
//             2-deep period-2 ring, per-lane pow2 scale w/ neighbor adoption).
//  waves1-7 : R0-R3 post-mortem: per-row cost was the L1 scatter-merge txn
//             machinery (~200cyc/row: 128 random label cols touch ~all 32
//             lines of the 2KB row). Fix: ingest rows COALESCED (2x b128,
//             8-deep MLP so HBM latency is paid once per chunk), bounce raw
//             row through per-wave LDS scratch, do the random-column select
//             as LDS reads (conflicts land on the parallel producer side,
//             not the serial chain - R1's lesson inverted), pack the same
//             (eb,e1,e3,pad) f4 ring.
// Math is bit-identical to R2 (same e-values, same recursion). One
// __syncthreads per 56-row chunk, 2-buffer ping/pong.
__global__ __launch_bounds__(512, 1) void ctc_alpha_kernel(
    const float* __restrict__ outputs, const int* __restrict__ labels,
    const int* __restrict__ out_lens, const int* __restrict__ lab_lens,
    float* __restrict__ ws, float* __restrict__ out)
{
    const int b    = blockIdx.x;
    const int tid  = threadIdx.x;
    const int wid  = tid >> 6;
    const int lane = tid & 63;

    int* cnt = (int*)ws;            // ws[0]: zeroed by hipMemsetAsync each launch
    float* losses = ws + 16;        // ws[16..79]: per-batch losses

    __shared__ f4_t  ring4[2][C_ * RW4_];   // 116,480 B
    __shared__ f4_t  scr[7][2][129];        //  28,896 B raw-row scratch (2064B/buf)
    __shared__ float save2[2];
    __shared__ int   saveE[2];
    __shared__ int   amLast;

    const int olen  = out_lens[b];
    const int ll    = lab_lens[b];
    const int s0q   = 2 * ll - 1;                 // odd
    const int s1q   = 2 * ll;                     // even, may be 256
    const int tlast = olen - 1;
    const int l0  = s0q >> 2, j0 = s0q & 3;
    const int l1e = (s1q == 256) ? 63 : (s1q >> 2);
    const int j1  = s1q & 3;
    const float* base = outputs + (size_t)b * T_ * V_;
    const int*   lab  = labels + b * L_;

    // per-lane label columns (consumer lane l's odd states)
    const int cA = lab[2 * lane];         // col for state 4l+1
    const int cB = lab[2 * lane + 1];     // col for state 4l+3

    // ---------------- consumer setup (wave 0) ----------------
    float sk1 = 0.f, sk3 = 0.f;
    float v0 = 0.f, v1 = 0.f, v2 = 0.f, v3 = 0.f, vx = 0.f;  // vx: state 256 (lane63)
    int   E = 0;                                             // per-lane scale
    const bool isl0 = (lane == 0);
    if (wid == 0) {
        __builtin_amdgcn_s_setprio(3);
        sk3 = (cB != cA) ? 1.f : 0.f;
        if (lane >= 1) sk1 = (cA != lab[2 * lane - 1]) ? 1.f : 0.f;
        if (isl0) {
            v0 = exp2_fast(base[0]      * LOG2E_);       // s=0 blank
            v1 = exp2_fast(base[lab[0]] * LOG2E_);       // s=1 first label
        }
        if (tlast == 0) {
            float w0 = (j0==0)?v0:(j0==1)?v1:(j0==2)?v2:v3;
            float w1 = (s1q==256) ? vx : ((j1==0)?v0:(j1==1)?v1:(j1==2)?v2:v3);
            if (lane == l0)  { save2[0] = w0; saveE[0] = E; }
            if (lane == l1e) { save2[1] = w1; saveE[1] = E; }
        }
    } else {
        __builtin_amdgcn_s_setprio(0);
    }

    // producer: coalesced-ingest + LDS-side select + pack.
    //  1) issue all 16 b128 row loads (8 rows, full MLP -> HBM latency once)
    //  2) write row m raw to scratch[m&1]; pack row m-1 from scratch[(m-1)&1]
    //     (reads trail writes by one buffer; compiler inserts lgkmcnt)
    auto produce = [&](int bb, int t0) {
        const int w1 = wid - 1;
        f4_t A[8], Cc[8];
        #pragma unroll
        for (int m = 0; m < 8; ++m) {
            int t = t0 + w1 + 7 * m;
            const f4_t* rp = (const f4_t*)((t < T_) ? (base + (size_t)t * V_) : base);
            A[m]  = rp[lane];          // cols 4*lane   .. 4*lane+3
            Cc[m] = rp[lane + 64];     // cols 256+4*lane ..
        }
        scr[w1][0][lane]      = A[0];      // conflict-free: 16B/lane contiguous
        scr[w1][0][lane + 64] = Cc[0];
        #pragma unroll
        for (int m = 1; m <= 8; ++m) {
            if (m < 8) {
                scr[w1][m & 1][lane]      = A[m];
                scr[w1][m & 1][lane + 64] = Cc[m];
            }
            int r = w1 + 7 * (m - 1);
            int t = t0 + r;
            if (t < T_) {
                const float* sf = (const float*)&scr[w1][(m - 1) & 1][0];
                float gb = sf[0];      // blank col: uniform -> broadcast
                float g1 = sf[cA];     // scattered: ~2-3-way conflicts, producer-side
                float g3 = sf[cB];
                f4_t e;
                e.x = exp2_fast(gb * LOG2E_);
                e.y = exp2_fast(g1 * LOG2E_);
                e.z = exp2_fast(g3 * LOG2E_);
                e.w = 0.f;
                ring4[bb][r * RW4_ + lane] = e;
            }
        }
    };

    // one recursion step with per-lane scale adoption (byte-identical to R2)
    auto step = [&](f4_t e) {
        float up1 = dpp_shr1_f(v3);           // state 4l-1 (lane0 -> 0)
        int   upE = dpp_shr1_i(E);
        upE = isl0 ? E : upE;                 // lane0: keep own scale

        int d    = upE - E;
        int mpos = (d > 0) ? d : 0;           // max(d,0)
        int sin  = (d < 0) ? d : 0;           // min(d,0)
        int sown = -mpos;
        E += mpos;
        v0 = ldx(v0, sown); v1 = ldx(v1, sown); v2 = ldx(v2, sown);
        v3 = ldx(v3, sown); vx = ldx(vx, sown);
        up1 = ldx(up1, sin);

        float n0 = (v0 + up1) * e.x;                   // even: no skip, blank col
        float n1 = fmaf(sk1, up1, v1 + v0) * e.y;      // skip from 4l-1 = up1
        float n2 = (v2 + v1) * e.x;                    // even: no skip, blank col
        float n3 = fmaf(sk3, v1, v3 + v2) * e.z;       // skip from 4l+1 = v1
        vx = (vx + v3) * e.x;                          // state 256 (blank col too)
        v0 = n0; v1 = n1; v2 = n2; v3 = n3;
    };

    auto renorm = [&]() {
        float mx = fmaxf(fmaxf(v0, v1), fmaxf(v2, v3));
        mx = fmaxf(mx, vx);
        int ex = (__float_as_int(mx) >> 23) - 126;     // 0 lanes: ex = -126
        v0 = ldx(v0, -ex); v1 = ldx(v1, -ex); v2 = ldx(v2, -ex); v3 = ldx(v3, -ex);
        vx = ldx(vx, -ex);
        E += ex;
    };

    auto consume = [&](int bb, int t0) {
        const f4_t* rp4 = &ring4[bb][lane];
        f4_t eb2[2];
        eb2[0] = rp4[0];
        eb2[1] = rp4[RW4_];

        bool chk = (t0 + C_ > T_) || ((unsigned)(tlast - t0) < (unsigned)C_);
        if (!chk) {
            #pragma unroll 8
            for (int r = 0; r < C_; ++r) {
                f4_t e = eb2[r & 1];
                if (r + 2 < C_) eb2[r & 1] = rp4[(r + 2) * RW4_];
                step(e);
                if ((r & 3) == 3) renorm();
            }
        } else {
            #pragma unroll 4
            for (int r = 0; r < C_; ++r) {
                int t = t0 + r;
                if (t >= T_) break;
                f4_t e = eb2[r & 1];
                if (r + 2 < C_) eb2[r & 1] = rp4[(r + 2) * RW4_];
                step(e);
                if ((r & 3) == 3) renorm();
                if (t == tlast) {
                    float w0 = (j0==0)?v0:(j0==1)?v1:(j0==2)?v2:v3;
                    float w1 = (s1q==256) ? vx : ((j1==0)?v0:(j1==1)?v1:(j1==2)?v2:v3);
                    if (lane == l0)  { save2[0] = w0; saveE[0] = E; }
                    if (lane == l1e) { save2[1] = w1; saveE[1] = E; }
                }
            }
        }
    };

    // ---------------- pipeline ----------------
    if (wid > 0) produce(0, 1);
    __syncthreads();
    for (int c = 0; c < NC_; ++c) {
        if (wid > 0) {
            if (c + 1 < NC_) produce((c + 1) & 1, 1 + (c + 1) * C_);
        } else {
            consume(c & 1, 1 + c * C_);
        }
        __syncthreads();
    }

    // ---------------- fused finish: per-batch loss + last-block mean ----------
    if (tid == 0) {
        float lx = log2_fast(save2[0]) + (float)saveE[0];
        float ly = log2_fast(save2[1]) + (float)saveE[1];
        float m  = fmaxf(lx, ly);
        float lik2 = m + log2_fast(exp2_fast(lx - m) + exp2_fast(ly - m));
        float loss = -(lik2 * LN2_) / (float)ll;
        __hip_atomic_store(&losses[b], loss, __ATOMIC_RELAXED, __HIP_MEMORY_SCOPE_AGENT);
        int old = __hip_atomic_fetch_add(cnt, 1, __ATOMIC_ACQ_REL, __HIP_MEMORY_SCOPE_AGENT);
        amLast = (old == B_ - 1);
    }
    __syncthreads();
    if (amLast && wid == 0) {
        float v = __hip_atomic_load(&losses[lane], __ATOMIC_RELAXED, __HIP_MEMORY_SCOPE_AGENT);
        #pragma unroll
        for (int o = 32; o > 0; o >>= 1) v += __shfl_down(v, o);
        if (lane == 0) out[0] = v * (1.0f / B_);
    }
}

extern "C" void kernel_launch(void* const* d_in, const int* in_sizes, int n_in,
                              void* d_out, int out_size, void* d_ws, size_t ws_size,
                              hipStream_t stream) {
    const float* outputs  = (const float*)d_in[0];
    const int*   labels   = (const int*)d_in[1];
    const int*   out_lens = (const int*)d_in[2];
    const int*   lab_lens = (const int*)d_in[3];

    (void)hipMemsetAsync(d_ws, 0, 64, stream);   // zero the completion counter
    ctc_alpha_kernel<<<B_, 512, 0, stream>>>(outputs, labels, out_lens, lab_lens,
                                             (float*)d_ws, (float*)d_out);
}